// Round 10
// baseline (255.784 us; speedup 1.0000x reference)
//
#include <hip/hip_runtime.h>
#include <cmath>

namespace {
constexpr int NELEM  = 50000;
constexpr int NSYN   = 500;
constexpr int NQ4    = 125;                 // NSYN/4
constexpr int T      = 1024;
constexpr int SBLK   = 49;                  // 49*1024 = 50176 >= NELEM
constexpr int SLOTS  = SBLK * T;            // 50176
constexpr int CMAXC  = (NELEM - 1) >> 6;    // 781 (64-elem chunks)
constexpr int NCH_PAD = 784;
constexpr int MAXSEG = 4096;
constexpr int NGRP   = NELEM / 8;           // 6250
constexpr double DELTA_D = 1.0e-3;
constexpr double THETA_D = 1.0;
constexpr float  DECAY_F = 0.90483741803595957311f;  // float32(exp(-1/10))
}

struct WS {
    double2 pq[SLOTS];            // (P,Q) entering element i
    double  rarr[SLOTS];          // R_i = Q_i - theta/P_i (contiguous)
    double  qarr[SLOTS];          // Q_i (contiguous; search Qr source)
    double  eAm[SLOTS], eAg[SLOTS], eAi[SLOTS];  // block-exclusive affine entries
    double  ePl[SLOTS], eQl[SLOTS];              // block-exclusive (p,q) entries
    double  gAm[64], gAg[64], gAi[64];   // 49 block aggregates (affine round)
    double  gEm[64], gEg[64], gEi[64];   // their exclusive entries (scanA tail)
    double  gPp[64], gPq[64];            // 49 block aggregates ((p,q) round)
    double  gEp[64], gEq[64];            // their exclusive entries (scanB tail)
    double  gmaxR[1024];                 // per-64-chunk max R
    double  gbndQ[MAXSEG];
    int     gbnd[MAXSEG];
    int     gnseg;
    int     ctrA, ctrB, ctrC;            // last-block counters (zeroed by k_rowdot)
    float   swv[SLOTS];
    float   iwv[SLOTS];
};

// ---------------- K1: per-timestep weighted row sums (R5-exact body) ----------------
__global__ __launch_bounds__(256) void k_rowdot(
    const float* __restrict__ spikes,
    const float* __restrict__ w,
    const float* __restrict__ vrev,
    WS* __restrict__ ws)
{
    if (blockIdx.x == 0 && threadIdx.x == 0) { ws->ctrA = 0; ws->ctrB = 0; ws->ctrC = 0; }

    const int lane = threadIdx.x & 63;
    const int wv   = threadIdx.x >> 6;
    const int rg   = blockIdx.x * 4 + wv;
    if (rg >= NGRP) return;
    const int row0 = rg * 8;

    const float4* __restrict__ w4 = reinterpret_cast<const float4*>(w);
    const float4* __restrict__ r4 = reinterpret_cast<const float4*>(vrev);
    const int j1 = lane;
    const int j2 = lane + 64;
    const bool has2 = (j2 < NQ4);
    float4 a1 = w4[j1], r1 = r4[j1];
    float4 aw1 = make_float4(fabsf(a1.x), fabsf(a1.y), fabsf(a1.z), fabsf(a1.w));
    float4 ar1 = make_float4(aw1.x * r1.x, aw1.y * r1.y, aw1.z * r1.z, aw1.w * r1.w);
    float4 aw2 = make_float4(0.f, 0.f, 0.f, 0.f), ar2 = aw2;
    if (has2) {
        float4 a2 = w4[j2], r2 = r4[j2];
        aw2 = make_float4(fabsf(a2.x), fabsf(a2.y), fabsf(a2.z), fabsf(a2.w));
        ar2 = make_float4(aw2.x * r2.x, aw2.y * r2.y, aw2.z * r2.z, aw2.w * r2.w);
    }

    float sp[8], ip[8];
#pragma unroll
    for (int r = 0; r < 8; ++r) {
        const float4* __restrict__ srow =
            reinterpret_cast<const float4*>(spikes + (size_t)(row0 + r) * NSYN);
        float4 s1 = srow[j1];
        float a = s1.x * aw1.x + s1.y * aw1.y + s1.z * aw1.z + s1.w * aw1.w;
        float b = s1.x * ar1.x + s1.y * ar1.y + s1.z * ar1.z + s1.w * ar1.w;
        if (has2) {
            float4 s2 = srow[j2];
            a += s2.x * aw2.x + s2.y * aw2.y + s2.z * aw2.z + s2.w * aw2.w;
            b += s2.x * ar2.x + s2.y * ar2.y + s2.z * ar2.z + s2.w * ar2.w;
        }
        sp[r] = a; ip[r] = b;
    }
#pragma unroll
    for (int d = 32; d > 0; d >>= 1) {
#pragma unroll
        for (int r = 0; r < 8; ++r) {
            sp[r] += __shfl_xor(sp[r], d);
            ip[r] += __shfl_xor(ip[r], d);
        }
    }
    if (lane == 0) {
        *reinterpret_cast<float4*>(ws->swv + row0)     = make_float4(sp[0], sp[1], sp[2], sp[3]);
        *reinterpret_cast<float4*>(ws->swv + row0 + 4) = make_float4(sp[4], sp[5], sp[6], sp[7]);
        *reinterpret_cast<float4*>(ws->iwv + row0)     = make_float4(ip[0], ip[1], ip[2], ip[3]);
        *reinterpret_cast<float4*>(ws->iwv + row0 + 4) = make_float4(ip[4], ip[5], ip[6], ip[7]);
    }
}

// last-block election helper (R9-verified pattern)
__device__ __forceinline__ bool last_block(int* ctr, int nblk) {
    __threadfence();                       // release this block's global writes
    __shared__ int s_last;
    if (threadIdx.x == 0) {
        int old = __hip_atomic_fetch_add(ctr, 1, __ATOMIC_ACQ_REL,
                                         __HIP_MEMORY_SCOPE_AGENT);
        s_last = (old == nblk - 1);
    }
    __syncthreads();
    return s_last != 0;
}

// ---------------- K2a: block-local affine scan + last-block aggA tail ----------------
__global__ __launch_bounds__(1024) void k_scanA(WS* __restrict__ ws)
{
    const int tid = threadIdx.x, lane = tid & 63, wv = tid >> 6, blk = blockIdx.x;
    const int idx = blk * T + tid;
    const bool live = (idx < NELEM);
    const double decay = (double)DECAY_F;
    __shared__ double s_a[16], s_b[16], s_c[16];

    double s = live ? (double)ws->swv[idx] : 0.0;
    double t = live ? (double)ws->iwv[idx] : 0.0;
    double m_in = live ? decay : 1.0;
    double g_in = live ? s * decay : 0.0;
    double i_in = live ? t * decay : 0.0;
#pragma unroll
    for (int d = 1; d < 64; d <<= 1) {
        double pm = __shfl_up(m_in, d);
        double pg = __shfl_up(g_in, d);
        double pi = __shfl_up(i_in, d);
        if (lane >= d) {
            g_in = m_in * pg + g_in;
            i_in = m_in * pi + i_in;
            m_in = pm * m_in;
        }
    }
    if (lane == 63) { s_a[wv] = m_in; s_b[wv] = g_in; s_c[wv] = i_in; }
    __syncthreads();
    if (wv == 0) {
        double wm = (lane < 16) ? s_a[lane] : 1.0;
        double wg = (lane < 16) ? s_b[lane] : 0.0;
        double wi = (lane < 16) ? s_c[lane] : 0.0;
#pragma unroll
        for (int d = 1; d < 16; d <<= 1) {
            double pm = __shfl_up(wm, d);
            double pg = __shfl_up(wg, d);
            double pi = __shfl_up(wi, d);
            if (lane >= d) {
                wg = wm * pg + wg;
                wi = wm * pi + wi;
                wm = pm * wm;
            }
        }
        if (lane < 16) { s_a[lane] = wm; s_b[lane] = wg; s_c[lane] = wi; }
        if (lane == 15) { ws->gAm[blk] = wm; ws->gAg[blk] = wg; ws->gAi[blk] = wi; }
    }
    __syncthreads();
    double em = __shfl_up(m_in, 1), eg = __shfl_up(g_in, 1), ei = __shfl_up(i_in, 1);
    if (lane == 0) { em = 1.0; eg = 0.0; ei = 0.0; }
    if (wv > 0) {
        double qm = s_a[wv - 1], qg = s_b[wv - 1], qi = s_c[wv - 1];
        eg = em * qg + eg;
        ei = em * qi + ei;
        em = qm * em;
    }
    ws->eAm[idx] = em; ws->eAg[idx] = eg; ws->eAi[idx] = ei;

    // ---- last-block tail: R5 k_aggA verbatim ----
    if (!last_block(&ws->ctrA, SBLK)) return;
    if (tid < 64) {
        double am = (lane < SBLK) ? ws->gAm[lane] : 1.0;
        double ag = (lane < SBLK) ? ws->gAg[lane] : 0.0;
        double ai = (lane < SBLK) ? ws->gAi[lane] : 0.0;
#pragma unroll
        for (int d = 1; d < 64; d <<= 1) {
            double pm = __shfl_up(am, d);
            double pg = __shfl_up(ag, d);
            double pi = __shfl_up(ai, d);
            if (lane >= d) {
                ag = am * pg + ag;
                ai = am * pi + ai;
                am = pm * am;
            }
        }
        double xm = __shfl_up(am, 1), xg = __shfl_up(ag, 1), xi = __shfl_up(ai, 1);
        if (lane == 0) { xm = 1.0; xg = 0.0; xi = 0.0; }
        if (lane < SBLK) { ws->gEm[lane] = xm; ws->gEg[lane] = xg; ws->gEi[lane] = xi; }
    }
}

// ---------------- K2b: (p,q) local scan + last-block aggB tail ----------------
__global__ __launch_bounds__(1024) void k_scanB(WS* __restrict__ ws)
{
    const int tid = threadIdx.x, lane = tid & 63, wv = tid >> 6, blk = blockIdx.x;
    const int idx = blk * T + tid;
    const bool live = (idx < NELEM);
    __shared__ double s_a[16], s_b[16];

    double em = ws->eAm[idx], eg = ws->eAg[idx], ei = ws->eAi[idx];
    double qg = ws->gEg[blk], qi = ws->gEi[blk];
    double Eg = em * qg + eg;            // global-exclusive exp traces (R5 order)
    double Ei = em * qi + ei;

    double p_in = 1.0, q_in = 0.0;
    if (live) {
        double aa = DELTA_D * (1.0 + Eg);
        double om = 1.0 - aa;
        p_in = om;
        q_in = (DELTA_D * Ei) / om;
    }
#pragma unroll
    for (int d = 1; d < 64; d <<= 1) {
        double pp = __shfl_up(p_in, d);
        double pq = __shfl_up(q_in, d);
        if (lane >= d) {
            q_in = pq + q_in / pp;
            p_in = pp * p_in;
        }
    }
    if (lane == 63) { s_a[wv] = p_in; s_b[wv] = q_in; }
    __syncthreads();
    if (wv == 0) {
        double wp = (lane < 16) ? s_a[lane] : 1.0;
        double wq = (lane < 16) ? s_b[lane] : 0.0;
#pragma unroll
        for (int d = 1; d < 16; d <<= 1) {
            double pp = __shfl_up(wp, d);
            double pq = __shfl_up(wq, d);
            if (lane >= d) {
                wq = pq + wq / pp;
                wp = pp * wp;
            }
        }
        if (lane < 16) { s_a[lane] = wp; s_b[lane] = wq; }
        if (lane == 15) { ws->gPp[blk] = wp; ws->gPq[blk] = wq; }
    }
    __syncthreads();
    double ep = __shfl_up(p_in, 1), eq = __shfl_up(q_in, 1);
    if (lane == 0) { ep = 1.0; eq = 0.0; }
    if (wv > 0) {
        double ap = s_a[wv - 1], aq = s_b[wv - 1];
        eq = aq + eq / ap;
        ep = ap * ep;
    }
    ws->ePl[idx] = ep; ws->eQl[idx] = eq;

    // ---- last-block tail: R5 k_aggB verbatim ----
    if (!last_block(&ws->ctrB, SBLK)) return;
    if (tid < 64) {
        double ap = (lane < SBLK) ? ws->gPp[lane] : 1.0;
        double aq = (lane < SBLK) ? ws->gPq[lane] : 0.0;
#pragma unroll
        for (int d = 1; d < 64; d <<= 1) {
            double pp = __shfl_up(ap, d);
            double pq = __shfl_up(aq, d);
            if (lane >= d) {
                aq = pq + aq / pp;
                ap = pp * ap;
            }
        }
        double xp = __shfl_up(ap, 1), xq = __shfl_up(aq, 1);
        if (lane == 0) { xp = 1.0; xq = 0.0; }
        if (lane < SBLK) { ws->gEp[lane] = xp; ws->gEq[lane] = xq; }
    }
}

// ---------------- K2c: apply + last-block serial search ----------------
__global__ __launch_bounds__(1024) void k_applyS(WS* __restrict__ ws)
{
    const int tid = threadIdx.x, lane = tid & 63, blk = blockIdx.x;
    const int idx = blk * T + tid;
    const bool live = (idx < NELEM);

    double pl = ws->ePl[idx], ql = ws->eQl[idx];
    double ap = ws->gEp[blk], aq = ws->gEq[blk];
    double Q = aq + ql / ap;
    double P = ap * pl;
    ws->pq[idx]   = make_double2(P, Q);
    ws->qarr[idx] = Q;
    double R = live ? (Q - THETA_D / P) : -1.0e308;
    ws->rarr[idx] = R;
    double mR = R;
#pragma unroll
    for (int d = 32; d > 0; d >>= 1) mR = fmax(mR, __shfl_xor(mR, d));
    if (lane == 0) ws->gmaxR[idx >> 6] = mR;

    // ---- last-block tail: serial segment search ----
    if (!last_block(&ws->ctrC, SBLK)) return;

    __shared__ double smax[NCH_PAD];
    for (int c = tid; c < NCH_PAD; c += T)
        smax[c] = (c <= CMAXC) ? ws->gmaxR[c] : -1.0e308;
    __syncthreads();

    if (tid < 64) {
        int nseg = 1;
        if (lane == 0) { ws->gbnd[0] = 0; ws->gbndQ[0] = 0.0; }
        double Qr = 0.0;
        int pos = 1;
        while (pos < NELEM && nseg < MAXSEG) {
            int c = pos >> 6;
            int i0 = -1;
            double qsave = 0.0;   // this lane's qarr value in the chunk that hit
            // probe the chunk containing pos (mask i >= pos); r & q loaded together
            {
                int i = (c << 6) + lane;
                bool inr = (i < NELEM);
                bool valid = inr && (i >= pos);
                double rv = valid ? ws->rarr[i] : -1.0e308;
                double qv = inr ? ws->qarr[i] : 0.0;
                unsigned long long m = __ballot(valid && (rv >= Qr));
                if (m) { i0 = (c << 6) + __builtin_ctzll(m); }
                qsave = qv;
            }
            while (i0 < 0) {
                int cf = -1;
                for (int cb = c + 1; cb <= CMAXC; cb += 64) {
                    int cc = cb + lane;
                    bool qy = (cc <= CMAXC) && (smax[cc] >= Qr);
                    unsigned long long m = __ballot(qy);
                    if (m) { cf = cb + __builtin_ctzll(m); break; }
                }
                if (cf < 0) break;
                c = cf;
                int i = (cf << 6) + lane;
                bool inr = (i < NELEM);
                double rv = inr ? ws->rarr[i] : -1.0e308;
                double qv = inr ? ws->qarr[i] : 0.0;
                unsigned long long m2 = __ballot(inr && (rv >= Qr));
                if (m2) { i0 = (cf << 6) + __builtin_ctzll(m2); qsave = qv; }
                // else: slack/masked false positive -> keep pruning from c+1
            }
            if (i0 < 0) break;
            int nb = i0 + 1;              // reset lands at nb
            if (nb >= NELEM) break;
            if ((i0 & 63) != 63) {
                Qr = __shfl(qsave, nb & 63);   // same chunk: no extra load
            } else {
                Qr = ws->qarr[nb];             // chunk boundary: one broadcast load
            }
            if (lane == 0) { ws->gbnd[nseg] = nb; ws->gbndQ[nseg] = Qr; }
            nseg++;
            pos = nb + 1;
        }
        if (lane == 0) ws->gnseg = nseg;
    }
}

// ---------------- K4: parallel fill ----------------
__global__ __launch_bounds__(1024) void k_fill(const WS* __restrict__ ws,
                                               float* __restrict__ out)
{
    __shared__ int    sb[MAXSEG];
    __shared__ double sq[MAXSEG];
    __shared__ int    s_nseg;
    const int tid = threadIdx.x;
    if (tid == 0) s_nseg = ws->gnseg;
    __syncthreads();
    const int nseg = s_nseg;
    for (int i = tid; i < nseg; i += T) { sb[i] = ws->gbnd[i]; sq[i] = ws->gbndQ[i]; }
    __syncthreads();

    const int idx = blockIdx.x * T + tid;
    if (idx < NELEM) {
        int lo = 0, hi = nseg - 1;
        while (lo < hi) {
            int mid = (lo + hi + 1) >> 1;
            if (sb[mid] <= idx) lo = mid; else hi = mid - 1;
        }
        if (idx == sb[lo]) {
            out[idx] = 0.0f;
        } else {
            double2 pl = ws->pq[idx];
            out[idx] = (float)(pl.x * (pl.y - sq[lo]));
        }
    }
}

extern "C" void kernel_launch(void* const* d_in, const int* in_sizes, int n_in,
                              void* d_out, int out_size, void* d_ws, size_t ws_size,
                              hipStream_t stream) {
    const float* spikes = (const float*)d_in[0];
    const float* w      = (const float*)d_in[1];
    const float* vrev   = (const float*)d_in[2];
    float* out = (float*)d_out;
    WS* ws = (WS*)d_ws;

    hipLaunchKernelGGL(k_rowdot, dim3((NGRP + 3) / 4), dim3(256), 0, stream,
                       spikes, w, vrev, ws);
    hipLaunchKernelGGL(k_scanA,  dim3(SBLK), dim3(T), 0, stream, ws);
    hipLaunchKernelGGL(k_scanB,  dim3(SBLK), dim3(T), 0, stream, ws);
    hipLaunchKernelGGL(k_applyS, dim3(SBLK), dim3(T), 0, stream, ws);
    hipLaunchKernelGGL(k_fill,   dim3(SBLK), dim3(T), 0, stream, ws, out);
}